// Round 25
// baseline (4707.245 us; speedup 1.0000x reference)
//
#include <hip/hip_runtime.h>
#include <stdint.h>

#define BATCH 8
#define NPTS  16384
#define BN    (BATCH * NPTS)
#define NT    512                 // 32-point tiles per batch
#define NTH   256                 // tiles per kh half
#define MARGIN 3.0e-3f            // > 2*delta_worst (2.6e-3), deterministic bound
#define QCAP  (1u << 20)          // queue capacity (4 MiB)

typedef float f32x16 __attribute__((ext_vector_type(16)));
typedef short s16x8  __attribute__((ext_vector_type(8)));

__device__ __forceinline__ uint16_t bfr(float x) {
    uint32_t u = __float_as_uint(x);
    return (uint16_t)((u + 0x7FFFu + ((u >> 16) & 1u)) >> 16);
}
__device__ __forceinline__ float bff(uint16_t s) {
    return __uint_as_float(((uint32_t)s) << 16);
}
__device__ __forceinline__ void split2(float v, uint16_t* a, uint16_t* b) {
    *a = bfr(v); *b = bfr(v - bff(*a));
}
__device__ __forceinline__ uint32_t pk2(uint16_t lo, uint16_t hi) {
    return (uint32_t)lo | ((uint32_t)hi << 16);
}
__device__ __forceinline__ uint32_t key32(float d) {
    uint32_t b = __float_as_uint(d);
    return (b & 0x80000000u) ? ~b : (b | 0x80000000u);
}
__device__ __forceinline__ float dec32(uint32_t k) {
    return __uint_as_float((k & 0x80000000u) ? (k ^ 0x80000000u) : ~k);
}

#define MIN3(a, b, c) fminf(fminf((a), (b)), (c))

__device__ __forceinline__ float fold16(const f32x16 a) {
    const float u0 = MIN3(a[0],  a[1],  a[2]);
    const float u1 = MIN3(a[3],  a[4],  a[5]);
    const float u2 = MIN3(a[6],  a[7],  a[8]);
    const float u3 = MIN3(a[9],  a[10], a[11]);
    const float u4 = MIN3(a[12], a[13], a[14]);
    const float v0 = MIN3(u0, u1, a[15]);
    const float v1 = MIN3(u2, u3, u4);
    return fminf(v0, v1);
}

// ---- enc2: [b][tile][64 uint4] — lane-linear A-fragments for streaming ----
// lane l<32: point tile*32+l, k-slots 0-7; lane l>=32: point tile*32+(l-32),
// k-slots 8-15. Wave load at (tilebase + l*16B) is one contiguous 1 KB line.
// slots = [1,1,Ya,Yb, H0,M0,H0,M0 | H1,M1,H1,M1, H2,M2,H2,M2]
__global__ __launch_bounds__(256) void enc_kernel(
    const float* __restrict__ Y, uint4* __restrict__ enc2,
    float4* __restrict__ y4)
{
#pragma clang fp contract(off)
    const int g = blockIdx.x * 256 + threadIdx.x;     // 0..BN-1
    const int b = g >> 14, p = g & (NPTS - 1);
    const float y0 = Y[(size_t)g * 3 + 0];
    const float y1 = Y[(size_t)g * 3 + 1];
    const float y2 = Y[(size_t)g * 3 + 2];
    const float ys = (y0 * y0 + y1 * y1) + y2 * y2;   // np order
    uint16_t Ya, Yb; split2(ys, &Ya, &Yb);
    uint16_t H0, M0; split2(-2.0f * y0, &H0, &M0);
    uint16_t H1, M1; split2(-2.0f * y1, &H1, &M1);
    uint16_t H2, M2; split2(-2.0f * y2, &H2, &M2);
    const uint16_t ONE = 0x3F80;
    const int tile = p >> 5, col = p & 31;
    const size_t base = ((size_t)b * NT + tile) * 64;
    enc2[base + col]      = make_uint4(pk2(ONE, ONE), pk2(Ya, Yb), pk2(H0, M0), pk2(H0, M0));
    enc2[base + 32 + col] = make_uint4(pk2(H1, M1), pk2(H1, M1), pk2(H2, M2), pk2(H2, M2));
    y4[g] = make_float4(y0, y1, y2, ys);
}

#define MKQFR(dst, qq) { \
        const float* xp = Xp + (size_t)(qq) * 3; \
        const float x0 = xp[0], x1 = xp[1], x2 = xp[2]; \
        const float xs = (x0 * x0 + x1 * x1) + x2 * x2; \
        uint16_t Xa, Xb; split2(xs, &Xa, &Xb); \
        uint16_t h0, m0; split2(x0, &h0, &m0); \
        uint16_t h1, m1; split2(x1, &h1, &m1); \
        uint16_t h2, m2; split2(x2, &h2, &m2); \
        const uint16_t ONE = 0x3F80; \
        if (hi == 0) { \
            dst[0]=(short)Xa; dst[1]=(short)Xb; dst[2]=(short)ONE; dst[3]=(short)ONE; \
            dst[4]=(short)h0; dst[5]=(short)h0; dst[6]=(short)m0;  dst[7]=(short)m0; \
        } else { \
            dst[0]=(short)h1; dst[1]=(short)h1; dst[2]=(short)m1;  dst[3]=(short)m1; \
            dst[4]=(short)h2; dst[5]=(short)h2; dst[6]=(short)m2;  dst[7]=(short)m2; \
        } }

#define SWEEP_DECODE() \
    const int tid = threadIdx.x; \
    const int l   = tid & 63; \
    const int wv  = tid >> 6; \
    const int col = l & 31; \
    const int hi  = l >> 5; \
    const int batch = blockIdx.x & 7; \
    const int kh    = (blockIdx.x >> 3) & 1; \
    const int xblk  = blockIdx.x >> 4; \
    const int qbase = batch * NPTS + xblk * 256 + wv * 64; \
    const uint4* pb = enc2 + ((size_t)batch * NT + (size_t)kh * NTH) * 64;

// ===== sweep1: streaming per-query approx min -> mkey (LDS-free) =====
__global__ __launch_bounds__(256, 4) void nn_sweep1(
    const float* __restrict__ Xp, const uint4* __restrict__ enc2,
    uint32_t* __restrict__ mkey)
{
#pragma clang fp contract(off)
    SWEEP_DECODE()

    const f32x16 zf = {0.f,0.f,0.f,0.f,0.f,0.f,0.f,0.f,
                       0.f,0.f,0.f,0.f,0.f,0.f,0.f,0.f};

    s16x8 qfr0, qfr1;
    MKQFR(qfr0, qbase + col)
    MKQFR(qfr1, qbase + 32 + col)

    float run0 = __builtin_inff(), run1 = __builtin_inff();

    uint4 n0 = pb[0 * 64 + l], n1 = pb[1 * 64 + l];
    uint4 n2 = pb[2 * 64 + l], n3 = pb[3 * 64 + l];
    for (int t = 0; t < NTH; t += 4) {
        const uint4 c0 = n0, c1 = n1, c2 = n2, c3 = n3;
        const uint4* nb = pb + (size_t)(t + 4) * 64;   // may read 4KB past half: valid ws
        n0 = nb[0 * 64 + l]; n1 = nb[1 * 64 + l];
        n2 = nb[2 * 64 + l]; n3 = nb[3 * 64 + l];
#define S1T(cq) { \
        const s16x8 pA = __builtin_bit_cast(s16x8, cq); \
        const f32x16 a0 = __builtin_amdgcn_mfma_f32_32x32x16_bf16(pA, qfr0, zf, 0, 0, 0); \
        run0 = fminf(run0, fold16(a0)); \
        const f32x16 a1 = __builtin_amdgcn_mfma_f32_32x32x16_bf16(pA, qfr1, zf, 0, 0, 0); \
        run1 = fminf(run1, fold16(a1)); }
        S1T(c0) S1T(c1) S1T(c2) S1T(c3)
#undef S1T
    }
    run0 = fminf(run0, __shfl_xor(run0, 32, 64));
    run1 = fminf(run1, __shfl_xor(run1, 32, 64));
    if (hi == 0) {
        atomicMin(&mkey[qbase + col],      key32(run0));
        atomicMin(&mkey[qbase + 32 + col], key32(run1));
    }
}

// ===== sweep2: streaming tile-flag -> queue of (q, 32-pt tile) =====
__global__ __launch_bounds__(256, 4) void nn_sweep2(
    const float* __restrict__ Xp, const uint4* __restrict__ enc2,
    const uint32_t* __restrict__ mkey, uint32_t* __restrict__ queue,
    uint32_t* __restrict__ qcount)
{
#pragma clang fp contract(off)
    SWEEP_DECODE()

    const f32x16 zf = {0.f,0.f,0.f,0.f,0.f,0.f,0.f,0.f,
                       0.f,0.f,0.f,0.f,0.f,0.f,0.f,0.f};

    s16x8 qfr0, qfr1;
    MKQFR(qfr0, qbase + col)
    MKQFR(qfr1, qbase + 32 + col)

    const float thr0 = dec32(mkey[qbase + col]) + MARGIN;
    const float thr1 = dec32(mkey[qbase + 32 + col]) + MARGIN;
    const int tbase = kh * NTH;

    uint4 n0 = pb[0 * 64 + l], n1 = pb[1 * 64 + l];
    uint4 n2 = pb[2 * 64 + l], n3 = pb[3 * 64 + l];
    for (int t = 0; t < NTH; t += 4) {
        const uint4 c0 = n0, c1 = n1, c2 = n2, c3 = n3;
        const uint4* nb = pb + (size_t)(t + 4) * 64;
        n0 = nb[0 * 64 + l]; n1 = nb[1 * 64 + l];
        n2 = nb[2 * 64 + l]; n3 = nb[3 * 64 + l];
#define S2T(cq, j) { \
        const s16x8 pA = __builtin_bit_cast(s16x8, cq); \
        const f32x16 a0 = __builtin_amdgcn_mfma_f32_32x32x16_bf16(pA, qfr0, zf, 0, 0, 0); \
        const f32x16 a1 = __builtin_amdgcn_mfma_f32_32x32x16_bf16(pA, qfr1, zf, 0, 0, 0); \
        float f0 = fold16(a0), f1 = fold16(a1); \
        f0 = fminf(f0, __shfl_xor(f0, 32, 64)); \
        f1 = fminf(f1, __shfl_xor(f1, 32, 64)); \
        if (hi == 0) { \
            const uint32_t tg = (uint32_t)(tbase + t + (j)); \
            if (f0 <= thr0) { \
                const uint32_t i = atomicAdd(qcount, 1u); \
                if (i < QCAP) queue[i] = ((uint32_t)(qbase + col) << 9) | tg; } \
            if (f1 <= thr1) { \
                const uint32_t i = atomicAdd(qcount, 1u); \
                if (i < QCAP) queue[i] = ((uint32_t)(qbase + 32 + col) << 9) | tg; } \
        } }
        S2T(c0, 0) S2T(c1, 1) S2T(c2, 2) S2T(c3, 3)
#undef S2T
    }
}

// ===== walk: one 32-lane group per entry; exact eval of its 32 points =====
__global__ __launch_bounds__(256, 8) void walk_kernel(
    const float* __restrict__ Xp, const float4* __restrict__ y4,
    const uint32_t* __restrict__ queue, const uint32_t* __restrict__ qcount,
    unsigned long long* __restrict__ gkeys)
{
#pragma clang fp contract(off)
    const int l32 = threadIdx.x & 31;
    const uint32_t grp = (blockIdx.x * 256 + threadIdx.x) >> 5;
    const uint32_t ngr = gridDim.x * 8;
    const uint32_t cnt = min(*qcount, QCAP);

    for (uint32_t e = grp; e < cnt; e += ngr) {
        const uint32_t entry = queue[e];
        const int q    = (int)(entry >> 9);
        const int tile = (int)(entry & 511);
        const int b    = q >> 14;

        const float* xp = Xp + (size_t)q * 3;
        const float qx0 = xp[0], qx1 = xp[1], qx2 = xp[2];
        const float qxs = (qx0 * qx0 + qx1 * qx1) + qx2 * qx2;  // np order

        const float4 yv = y4[(size_t)b * NPTS + (size_t)tile * 32 + l32];
        // bit-exact reference chain (validated R2..R24)
        const float dd = (qxs - 2.0f * ((qx0 * yv.x + qx1 * yv.y) + qx2 * yv.z)) + yv.w;
        unsigned long long best =
            ((unsigned long long)key32(dd) << 32) |
            (uint32_t)((tile * 32 + l32) & (NPTS - 1));
#pragma unroll
        for (int m = 1; m <= 16; m <<= 1) {
            const unsigned long long o = __shfl_xor(best, m, 64);
            if (o < best) best = o;
        }
        if (l32 == 0) atomicMin(&gkeys[q], best);
    }
}

// ---- final: gkeys -> (dist, idx) for one direction ----
__global__ __launch_bounds__(256) void writeout_k(
    const unsigned long long* __restrict__ gkeys, float* __restrict__ out, int dir)
{
    const size_t q = (size_t)blockIdx.x * 256 + threadIdx.x;   // 0..BN-1
    const unsigned long long m = gkeys[q];
    out[(size_t)dir * BN + q]       = dec32((uint32_t)(m >> 32));
    out[(size_t)(2 + dir) * BN + q] = (float)(uint32_t)(m & 0xFFFFFFFFu);
}

extern "C" void kernel_launch(void* const* d_in, const int* in_sizes, int n_in,
                              void* d_out, int out_size, void* d_ws, size_t ws_size,
                              hipStream_t stream) {
    const float* xyz1 = (const float*)d_in[0];
    const float* xyz2 = (const float*)d_in[1];
    float* out = (float*)d_out;

    // ws layout (11.5 MiB + eps; ws >= 16 MiB proven R22-R24):
    // enc2 4M | y4 2M | mkey 0.5M | gkeys 1M | queue 4M | qcount
    char* base = (char*)d_ws;
    uint4*    enc2  = (uint4*)base;
    float4*   y4    = (float4*)(base + (size_t)4 * 1024 * 1024);
    uint32_t* mkey  = (uint32_t*)(base + (size_t)6 * 1024 * 1024);
    unsigned long long* gkeys =
        (unsigned long long*)(base + (size_t)6 * 1024 * 1024 + 512 * 1024);
    uint32_t* queue  = (uint32_t*)(base + (size_t)7 * 1024 * 1024 + 512 * 1024);
    uint32_t* qcount = (uint32_t*)(base + (size_t)11 * 1024 * 1024 + 512 * 1024);

    for (int dir = 0; dir < 2; ++dir) {
        const float* Xq = dir ? xyz2 : xyz1;   // queries
        const float* Yp = dir ? xyz1 : xyz2;   // points

        hipMemsetAsync(mkey, 0xFF, (size_t)BN * 4, stream);
        hipMemsetAsync(gkeys, 0xFF, (size_t)BN * 8, stream);
        hipMemsetAsync(qcount, 0, 256, stream);

        enc_kernel<<<BN / 256, 256, 0, stream>>>(Yp, enc2, y4);
        nn_sweep1<<<1024, 256, 0, stream>>>(Xq, enc2, mkey);
        nn_sweep2<<<1024, 256, 0, stream>>>(Xq, enc2, mkey, queue, qcount);
        walk_kernel<<<2048, 256, 0, stream>>>(Xq, y4, queue, qcount, gkeys);
        writeout_k<<<BN / 256, 256, 0, stream>>>(gkeys, out, dir);
    }
}

// Round 26
// 373.200 us; speedup vs baseline: 12.6132x; 12.6132x over previous
//
#include <hip/hip_runtime.h>
#include <stdint.h>

#define BATCH 8
#define NPTS  16384
#define BN    (BATCH * NPTS)
#define NT    512                 // 32-point tiles per batch
#define NTH   256                 // tiles per kh half
#define QPB   256                 // queries per block
#define MARGIN 3.0e-3f            // > 2*delta_worst (2.6e-3), deterministic bound

typedef float f32x16 __attribute__((ext_vector_type(16)));
typedef short s16x8  __attribute__((ext_vector_type(8)));

__device__ __forceinline__ uint16_t bfr(float x) {
    uint32_t u = __float_as_uint(x);
    return (uint16_t)((u + 0x7FFFu + ((u >> 16) & 1u)) >> 16);
}
__device__ __forceinline__ float bff(uint16_t s) {
    return __uint_as_float(((uint32_t)s) << 16);
}
__device__ __forceinline__ void split2(float v, uint16_t* a, uint16_t* b) {
    *a = bfr(v); *b = bfr(v - bff(*a));
}
__device__ __forceinline__ uint32_t pk2(uint16_t lo, uint16_t hi) {
    return (uint32_t)lo | ((uint32_t)hi << 16);
}
__device__ __forceinline__ uint32_t key32(float d) {
    uint32_t b = __float_as_uint(d);
    return (b & 0x80000000u) ? ~b : (b | 0x80000000u);
}
__device__ __forceinline__ float dec32(uint32_t k) {
    return __uint_as_float((k & 0x80000000u) ? (k ^ 0x80000000u) : ~k);
}

#define F16(M_) M_(0) M_(1) M_(2) M_(3) M_(4) M_(5) M_(6) M_(7) \
                M_(8) M_(9) M_(10) M_(11) M_(12) M_(13) M_(14) M_(15)

#define MIN3(a, b, c) fminf(fminf((a), (b)), (c))

__device__ __forceinline__ float fold16(const f32x16 a) {
    const float u0 = MIN3(a[0],  a[1],  a[2]);
    const float u1 = MIN3(a[3],  a[4],  a[5]);
    const float u2 = MIN3(a[6],  a[7],  a[8]);
    const float u3 = MIN3(a[9],  a[10], a[11]);
    const float u4 = MIN3(a[12], a[13], a[14]);
    const float v0 = MIN3(u0, u1, a[15]);
    const float v1 = MIN3(u2, u3, u4);
    return fminf(v0, v1);
}

// ---- enc2: [b][tile][64 uint4] lane-linear A-fragments + y4 table ----
// lane l<32: point tile*32+l, k-slots 0-7; lane l>=32: same point set, slots 8-15.
__global__ __launch_bounds__(256) void enc_kernel(
    const float* __restrict__ Y, uint4* __restrict__ enc2,
    float4* __restrict__ y4)
{
#pragma clang fp contract(off)
    const int g = blockIdx.x * 256 + threadIdx.x;     // 0..BN-1
    const int b = g >> 14, p = g & (NPTS - 1);
    const float y0 = Y[(size_t)g * 3 + 0];
    const float y1 = Y[(size_t)g * 3 + 1];
    const float y2 = Y[(size_t)g * 3 + 2];
    const float ys = (y0 * y0 + y1 * y1) + y2 * y2;   // np order
    uint16_t Ya, Yb; split2(ys, &Ya, &Yb);
    uint16_t H0, M0; split2(-2.0f * y0, &H0, &M0);
    uint16_t H1, M1; split2(-2.0f * y1, &H1, &M1);
    uint16_t H2, M2; split2(-2.0f * y2, &H2, &M2);
    const uint16_t ONE = 0x3F80;
    const int tile = p >> 5, col = p & 31;
    const size_t base = ((size_t)b * NT + tile) * 64;
    enc2[base + col]      = make_uint4(pk2(ONE, ONE), pk2(Ya, Yb), pk2(H0, M0), pk2(H0, M0));
    enc2[base + 32 + col] = make_uint4(pk2(H1, M1), pk2(H1, M1), pk2(H2, M2), pk2(H2, M2));
    y4[g] = make_float4(y0, y1, y2, ys);
}

#define MKQFR(dst, qq) { \
        const float* xp = Xp + (size_t)(qq) * 3; \
        const float x0 = xp[0], x1 = xp[1], x2 = xp[2]; \
        const float xs = (x0 * x0 + x1 * x1) + x2 * x2; \
        uint16_t Xa, Xb; split2(xs, &Xa, &Xb); \
        uint16_t h0, m0; split2(x0, &h0, &m0); \
        uint16_t h1, m1; split2(x1, &h1, &m1); \
        uint16_t h2, m2; split2(x2, &h2, &m2); \
        const uint16_t ONE = 0x3F80; \
        if (hi == 0) { \
            dst[0]=(short)Xa; dst[1]=(short)Xb; dst[2]=(short)ONE; dst[3]=(short)ONE; \
            dst[4]=(short)h0; dst[5]=(short)h0; dst[6]=(short)m0;  dst[7]=(short)m0; \
        } else { \
            dst[0]=(short)h1; dst[1]=(short)h1; dst[2]=(short)m1;  dst[3]=(short)m1; \
            dst[4]=(short)h2; dst[5]=(short)h2; dst[6]=(short)m2;  dst[7]=(short)m2; \
        } }

#define SWEEP_DECODE() \
    const int tid = threadIdx.x; \
    const int l   = tid & 63; \
    const int wv  = tid >> 6; \
    const int col = l & 31; \
    const int hi  = l >> 5; \
    const int batch = blockIdx.x & 7; \
    const int kh    = (blockIdx.x >> 3) & 1; \
    const int xblk  = blockIdx.x >> 4; \
    const int qbase = batch * NPTS + xblk * QPB + wv * 64; \
    const uint4* pb = enc2 + ((size_t)batch * NT + (size_t)kh * NTH) * 64;

// ===== sweep1: streaming per-query approx min -> mkey (validated fast in R25) =====
__global__ __launch_bounds__(256, 4) void nn_sweep1(
    const float* __restrict__ Xp, const uint4* __restrict__ enc2,
    uint32_t* __restrict__ mkey)
{
#pragma clang fp contract(off)
    SWEEP_DECODE()

    const f32x16 zf = {0.f,0.f,0.f,0.f,0.f,0.f,0.f,0.f,
                       0.f,0.f,0.f,0.f,0.f,0.f,0.f,0.f};

    s16x8 qfr0, qfr1;
    MKQFR(qfr0, qbase + col)
    MKQFR(qfr1, qbase + 32 + col)

    float run0 = __builtin_inff(), run1 = __builtin_inff();

    uint4 n0 = pb[0 * 64 + l], n1 = pb[1 * 64 + l];
    uint4 n2 = pb[2 * 64 + l], n3 = pb[3 * 64 + l];
    for (int t = 0; t < NTH; t += 4) {
        const uint4 c0 = n0, c1 = n1, c2 = n2, c3 = n3;
        const uint4* nb = pb + (size_t)(t + 4) * 64;   // tail reads land in valid ws
        n0 = nb[0 * 64 + l]; n1 = nb[1 * 64 + l];
        n2 = nb[2 * 64 + l]; n3 = nb[3 * 64 + l];
#define S1T(cq) { \
        const s16x8 pA = __builtin_bit_cast(s16x8, cq); \
        const f32x16 a0 = __builtin_amdgcn_mfma_f32_32x32x16_bf16(pA, qfr0, zf, 0, 0, 0); \
        run0 = fminf(run0, fold16(a0)); \
        const f32x16 a1 = __builtin_amdgcn_mfma_f32_32x32x16_bf16(pA, qfr1, zf, 0, 0, 0); \
        run1 = fminf(run1, fold16(a1)); }
        S1T(c0) S1T(c1) S1T(c2) S1T(c3)
#undef S1T
    }
    run0 = fminf(run0, __shfl_xor(run0, 32, 64));
    run1 = fminf(run1, __shfl_xor(run1, 32, 64));
    if (hi == 0) {
        atomicMin(&mkey[qbase + col],      key32(run0));
        atomicMin(&mkey[qbase + 32 + col], key32(run1));
    }
}

// ===== sweep2: streaming + inline exact HIT walk into LDS keys (no queue) =====
__global__ __launch_bounds__(256, 4) void nn_sweep2(
    const float* __restrict__ Xp, const uint4* __restrict__ enc2,
    const float4* __restrict__ y4, const uint32_t* __restrict__ mkey,
    unsigned long long* __restrict__ gkeys)
{
#pragma clang fp contract(off)
    __shared__ unsigned long long keys[QPB];           // 2 KB, ONLY shared state
    SWEEP_DECODE()

    const float4* Y4 = y4 + (size_t)batch * NPTS;

    keys[tid] = ~0ull;

    const f32x16 zf = {0.f,0.f,0.f,0.f,0.f,0.f,0.f,0.f,
                       0.f,0.f,0.f,0.f,0.f,0.f,0.f,0.f};

    // A-side (point) row calibration, packed 16 x 8 bits
    int rowpack[4] = {0, 0, 0, 0};
    {
        s16x8 pa = {0,0,0,0,0,0,0,0}, pbq = {0,0,0,0,0,0,0,0};
        if (hi == 0) { pa[0] = (short)bfr((float)col); pbq[0] = (short)0x3F80; }
        const f32x16 rowp = __builtin_amdgcn_mfma_f32_32x32x16_bf16(pa, pbq, zf, 0, 0, 0);
#define PR(i) rowpack[(i) >> 2] |= ((int)rowp[i] & 0xFF) << (((i) & 3) * 8);
        F16(PR)
#undef PR
    }

    s16x8 qfr0, qfr1;
    float qa0, qa1, qa2, qas, qb0, qb1, qb2, qbs;
    {
        const float* xp = Xp + (size_t)(qbase + col) * 3;
        qa0 = xp[0]; qa1 = xp[1]; qa2 = xp[2];
        qas = (qa0 * qa0 + qa1 * qa1) + qa2 * qa2;
    }
    {
        const float* xp = Xp + (size_t)(qbase + 32 + col) * 3;
        qb0 = xp[0]; qb1 = xp[1]; qb2 = xp[2];
        qbs = (qb0 * qb0 + qb1 * qb1) + qb2 * qb2;
    }
    MKQFR(qfr0, qbase + col)
    MKQFR(qfr1, qbase + 32 + col)

    const float thr0 = dec32(mkey[qbase + col]) + MARGIN;
    const float thr1 = dec32(mkey[qbase + 32 + col]) + MARGIN;

    __syncthreads();                                   // keys[] initialized

#define HITR(accv, jb, foff, thr, qx0, qx1, qx2, qxs, r) \
        if ((accv)[r] <= (thr)) { \
            const int jc = (jb) + ((rowpack[(r) >> 2] >> (((r) & 3) * 8)) & 0xFF); \
            const float4 yv = Y4[jc]; \
            const float dd = ((qxs) - 2.0f * (((qx0) * yv.x + (qx1) * yv.y) + (qx2) * yv.z)) + yv.w; \
            atomicMin(&keys[wv * 64 + (foff) + col], \
                      ((unsigned long long)key32(dd) << 32) | (uint32_t)jc); }
#define HIT(accv, jb, foff, thr, qx0, qx1, qx2, qxs) \
        if (fold16(accv) <= (thr)) { \
            HITR(accv, jb, foff, thr, qx0, qx1, qx2, qxs, 0) \
            HITR(accv, jb, foff, thr, qx0, qx1, qx2, qxs, 1) \
            HITR(accv, jb, foff, thr, qx0, qx1, qx2, qxs, 2) \
            HITR(accv, jb, foff, thr, qx0, qx1, qx2, qxs, 3) \
            HITR(accv, jb, foff, thr, qx0, qx1, qx2, qxs, 4) \
            HITR(accv, jb, foff, thr, qx0, qx1, qx2, qxs, 5) \
            HITR(accv, jb, foff, thr, qx0, qx1, qx2, qxs, 6) \
            HITR(accv, jb, foff, thr, qx0, qx1, qx2, qxs, 7) \
            HITR(accv, jb, foff, thr, qx0, qx1, qx2, qxs, 8) \
            HITR(accv, jb, foff, thr, qx0, qx1, qx2, qxs, 9) \
            HITR(accv, jb, foff, thr, qx0, qx1, qx2, qxs, 10) \
            HITR(accv, jb, foff, thr, qx0, qx1, qx2, qxs, 11) \
            HITR(accv, jb, foff, thr, qx0, qx1, qx2, qxs, 12) \
            HITR(accv, jb, foff, thr, qx0, qx1, qx2, qxs, 13) \
            HITR(accv, jb, foff, thr, qx0, qx1, qx2, qxs, 14) \
            HITR(accv, jb, foff, thr, qx0, qx1, qx2, qxs, 15) \
        }

    uint4 n0 = pb[0 * 64 + l], n1 = pb[1 * 64 + l];
    for (int t = 0; t < NTH; t += 2) {
        const uint4 c0 = n0, c1 = n1;
        const uint4* nb = pb + (size_t)(t + 2) * 64;   // tail reads land in valid ws
        n0 = nb[0 * 64 + l]; n1 = nb[1 * 64 + l];
#define S2T(cq, j) { \
        const s16x8 pA = __builtin_bit_cast(s16x8, cq); \
        const int jb = (kh * NTH + t + (j)) * 32; \
        const f32x16 a0 = __builtin_amdgcn_mfma_f32_32x32x16_bf16(pA, qfr0, zf, 0, 0, 0); \
        HIT(a0, jb, 0, thr0, qa0, qa1, qa2, qas) \
        const f32x16 a1 = __builtin_amdgcn_mfma_f32_32x32x16_bf16(pA, qfr1, zf, 0, 0, 0); \
        HIT(a1, jb, 32, thr1, qb0, qb1, qb2, qbs) }
        S2T(c0, 0) S2T(c1, 1)
#undef S2T
    }
#undef HIT
#undef HITR

    __syncthreads();
    {
        const unsigned long long m = keys[tid];
        atomicMin(&gkeys[(size_t)batch * NPTS + xblk * QPB + tid], m);
    }
}

// ---- final: gkeys -> (dist, idx) for one direction ----
__global__ __launch_bounds__(256) void writeout_k(
    const unsigned long long* __restrict__ gkeys, float* __restrict__ out, int dir)
{
    const size_t q = (size_t)blockIdx.x * 256 + threadIdx.x;   // 0..BN-1
    const unsigned long long m = gkeys[q];
    out[(size_t)dir * BN + q]       = dec32((uint32_t)(m >> 32));
    out[(size_t)(2 + dir) * BN + q] = (float)(uint32_t)(m & 0xFFFFFFFFu);
}

extern "C" void kernel_launch(void* const* d_in, const int* in_sizes, int n_in,
                              void* d_out, int out_size, void* d_ws, size_t ws_size,
                              hipStream_t stream) {
    const float* xyz1 = (const float*)d_in[0];
    const float* xyz2 = (const float*)d_in[1];
    float* out = (float*)d_out;

    // ws layout: enc2 4M | y4 2M | mkey 0.5M | gkeys 1M  (7.5 MiB total)
    char* base = (char*)d_ws;
    uint4*    enc2 = (uint4*)base;
    float4*   y4   = (float4*)(base + (size_t)4 * 1024 * 1024);
    uint32_t* mkey = (uint32_t*)(base + (size_t)6 * 1024 * 1024);
    unsigned long long* gkeys =
        (unsigned long long*)(base + (size_t)6 * 1024 * 1024 + 512 * 1024);

    for (int dir = 0; dir < 2; ++dir) {
        const float* Xq = dir ? xyz2 : xyz1;   // queries
        const float* Yp = dir ? xyz1 : xyz2;   // points

        hipMemsetAsync(mkey, 0xFF, (size_t)BN * 4, stream);
        hipMemsetAsync(gkeys, 0xFF, (size_t)BN * 8, stream);

        enc_kernel<<<BN / 256, 256, 0, stream>>>(Yp, enc2, y4);
        nn_sweep1<<<1024, 256, 0, stream>>>(Xq, enc2, mkey);
        nn_sweep2<<<1024, 256, 0, stream>>>(Xq, enc2, y4, mkey, gkeys);
        writeout_k<<<BN / 256, 256, 0, stream>>>(gkeys, out, dir);
    }
}